// Round 1
// baseline (659.290 us; speedup 1.0000x reference)
//
#include <hip/hip_runtime.h>

#define DI __device__ __forceinline__

typedef __bf16 bf16x8 __attribute__((ext_vector_type(8)));
typedef float f32x4 __attribute__((ext_vector_type(4)));

DI ushort f2bf(float f) {
  unsigned u = __builtin_bit_cast(unsigned, f);
  unsigned r = (u + 0x7FFFu + ((u >> 16) & 1u)) >> 16;
  return (ushort)r;
}

DI void gload_lds16(const void* g, void* l) {
  __builtin_amdgcn_global_load_lds(
      (const __attribute__((address_space(1))) unsigned*)g,
      (__attribute__((address_space(3))) unsigned*)l, 16, 0, 0);
}

DI bf16x8 load_frag(const ushort* p) { return *(const bf16x8*)p; }

// ---------------- convert x (f32 -> bf16), 4 elems/thread ----------------
__global__ __launch_bounds__(256) void k_convert_x(const float* __restrict__ x,
                                                   ushort* __restrict__ xb) {
  int i = (blockIdx.x * 256 + threadIdx.x) * 4;
  float4 v = *(const float4*)(x + i);
  ushort4 o;
  o.x = f2bf(v.x); o.y = f2bf(v.y); o.z = f2bf(v.z); o.w = f2bf(v.w);
  *(ushort4*)(xb + i) = o;
}

// ------- transpose-convert W[k][n] f32 -> Wt[n][k] bf16 (1024x1024) -------
__global__ __launch_bounds__(256) void k_transpose_w(const float* __restrict__ W,
                                                     ushort* __restrict__ Wt) {
  __shared__ float tile[64][65];
  int k0 = (blockIdx.x & 15) << 6;
  int n0 = (blockIdx.x >> 4) << 6;
  int c = threadIdx.x & 63;
  int r0 = threadIdx.x >> 6;
#pragma unroll
  for (int i = 0; i < 16; ++i) {
    int r = i * 4 + r0;
    tile[r][c] = W[(k0 + r) * 1024 + n0 + c];
  }
  __syncthreads();
#pragma unroll
  for (int i = 0; i < 16; ++i) {
    int nn = i * 4 + r0;
    Wt[(n0 + nn) * 1024 + k0 + c] = f2bf(tile[c][nn]);
  }
}

// ---------------- GEMM: C[M=8192,N=1024] = A[M,K=1024] @ Bt[N,K]^T + bias ----------------
// MODE 0: fp32 row-major out.  MODE 1: bf16 -> [B,H,S,D].  MODE 2: bf16 -> [B,H,D,S].
// m97 structure: 128x128 tile, BK=64, 4 waves (2x2 of 64x64), global_load_lds w16,
// XOR-swizzled LDS (chunk ^= row&7) per G4/G21 (linear dest + inverse-swz source + swz read).
template <int MODE>
__global__ __launch_bounds__(256, 2) void k_gemm(const ushort* __restrict__ A,
                                                 const ushort* __restrict__ Bt,
                                                 const float* __restrict__ bias,
                                                 void* __restrict__ out) {
  __shared__ ushort Asm[8192];  // [128 rows][64 k] bf16, swizzled
  __shared__ ushort Bsm[8192];
  int L = blockIdx.x;
  int wg = (L & 7) * 64 + (L >> 3);  // bijective XCD swizzle (512 % 8 == 0)
  int brow = wg >> 3;                // 0..63
  int bcol = wg & 7;                 // 0..7
  int tid = threadIdx.x;
  int w = tid >> 6, lane = tid & 63;
  int g = lane >> 4, lr = lane & 15;
  int wr = w >> 1, wc = w & 1;
  const char* Abase = (const char*)(A + (size_t)brow * 128 * 1024);
  const char* Bbase = (const char*)(Bt + (size_t)bcol * 128 * 1024);
  f32x4 acc[4][4] = {};
  for (int kt = 0; kt < 16; ++kt) {
    int k0b = kt * 128;  // byte offset along K
#pragma unroll
    for (int i = 0; i < 4; ++i) {
      int j = w * 4 + i;             // 16 slots of 1 KiB
      int fo = j * 1024 + lane * 16; // linear LDS dest byte
      int row = fo >> 7;
      int cis = ((fo >> 4) & 7) ^ (row & 7);  // inverse-swizzled source chunk
      long srcoff = (long)row * 2048 + k0b + cis * 16;
      gload_lds16(Abase + srcoff, (char*)Asm + j * 1024);
      gload_lds16(Bbase + srcoff, (char*)Bsm + j * 1024);
    }
    __syncthreads();
#pragma unroll
    for (int ks = 0; ks < 2; ++ks) {
      bf16x8 af[4], bfr[4];
#pragma unroll
      for (int m = 0; m < 4; ++m) {
        int row = wr * 64 + m * 16 + lr;
        int ci = (ks * 4 + g) ^ (row & 7);
        af[m] = *(const bf16x8*)((const char*)Asm + row * 128 + ci * 16);
      }
#pragma unroll
      for (int n = 0; n < 4; ++n) {
        int row = wc * 64 + n * 16 + lr;
        int ci = (ks * 4 + g) ^ (row & 7);
        bfr[n] = *(const bf16x8*)((const char*)Bsm + row * 128 + ci * 16);
      }
#pragma unroll
      for (int m = 0; m < 4; ++m)
#pragma unroll
        for (int n = 0; n < 4; ++n)
          acc[m][n] = __builtin_amdgcn_mfma_f32_16x16x32_bf16(af[m], bfr[n], acc[m][n], 0, 0, 0);
    }
    __syncthreads();
  }
  // epilogue: C/D layout col = lane&15, row = (lane>>4)*4 + r  [m89-verified]
#pragma unroll
  for (int m = 0; m < 4; ++m) {
#pragma unroll
    for (int n = 0; n < 4; ++n) {
      int Cc = bcol * 128 + wc * 64 + n * 16 + lr;
      float bv = bias[Cc];
#pragma unroll
      for (int r = 0; r < 4; ++r) {
        int R = brow * 128 + wr * 64 + m * 16 + g * 4 + r;
        float v = acc[m][n][r] + bv;
        if (MODE == 0) {
          ((float*)out)[(size_t)R * 1024 + Cc] = v;
        } else if (MODE == 1) {
          int b = R >> 11, s = R & 2047, h = Cc >> 6, d = Cc & 63;
          ((ushort*)out)[(((size_t)(b * 16 + h) * 2048 + s) << 6) + d] = f2bf(v);
        } else {
          int b = R >> 11, s = R & 2047, h = Cc >> 6, d = Cc & 63;
          ((ushort*)out)[(((size_t)(b * 16 + h) * 64 + d) << 11) + s] = f2bf(v);
        }
      }
    }
  }
}

// ---------------- flash attention ----------------
// grid 2048: each block = one (b,h, 64-row q-tile); 4 waves x 16 q-rows.
// K/V read direct from global (L2-resident per XCD via L%8 grouping).
// Online softmax wave-parallel via 16-lane shfl_xor; P -> swizzled LDS -> A-frags.
__global__ __launch_bounds__(256, 2) void k_attn(const ushort* __restrict__ Qb,
                                                 const ushort* __restrict__ Kb,
                                                 const ushort* __restrict__ Vt,
                                                 ushort* __restrict__ aout) {
  __shared__ ushort Psm[4][2048];  // per-wave 16x128 bf16, rows 256B, swizzled
  int L = blockIdx.x;
  int mm = L >> 3;
  int bh = (L & 7) * 8 + (mm >> 5);  // all 32 q-tiles of a bh on one XCD
  int qt = mm & 31;
  int b = bh >> 4, h = bh & 15;
  int tid = threadIdx.x;
  int w = tid >> 6, lane = tid & 63, g = lane >> 4, lr = lane & 15;
  const ushort* Qp = Qb + (size_t)bh * 2048 * 64;
  const ushort* Kp = Kb + (size_t)bh * 2048 * 64;
  const ushort* Vp = Vt + (size_t)bh * 64 * 2048;
  int sq0 = qt * 64 + w * 16;
  bf16x8 qa[2];
#pragma unroll
  for (int ks = 0; ks < 2; ++ks)
    qa[ks] = load_frag(Qp + (sq0 + lr) * 64 + ks * 32 + g * 8);
  float mrow[4], lsum[4];
  f32x4 oacc[4] = {};
#pragma unroll
  for (int r = 0; r < 4; ++r) { mrow[r] = -1e30f; lsum[r] = 0.f; }
  ushort* Pw = &Psm[w][0];
  for (int t0 = 0; t0 < 2048; t0 += 128) {
    f32x4 sacc[8] = {};
#pragma unroll
    for (int ct = 0; ct < 8; ++ct) {
#pragma unroll
      for (int ks = 0; ks < 2; ++ks) {
        bf16x8 kb = load_frag(Kp + (t0 + ct * 16 + lr) * 64 + ks * 32 + g * 8);
        sacc[ct] = __builtin_amdgcn_mfma_f32_16x16x32_bf16(qa[ks], kb, sacc[ct], 0, 0, 0);
      }
    }
    float pv[8][4];
#pragma unroll
    for (int ct = 0; ct < 8; ++ct)
#pragma unroll
      for (int r = 0; r < 4; ++r) pv[ct][r] = sacc[ct][r] * 0.125f;  // 1/sqrt(64)
    float corr[4];
#pragma unroll
    for (int r = 0; r < 4; ++r) {
      float pm = pv[0][r];
#pragma unroll
      for (int ct = 1; ct < 8; ++ct) pm = fmaxf(pm, pv[ct][r]);
      pm = fmaxf(pm, __shfl_xor(pm, 1, 64));
      pm = fmaxf(pm, __shfl_xor(pm, 2, 64));
      pm = fmaxf(pm, __shfl_xor(pm, 4, 64));
      pm = fmaxf(pm, __shfl_xor(pm, 8, 64));
      float mnew = fmaxf(mrow[r], pm);
      corr[r] = __expf(mrow[r] - mnew);  // first iter: exp(-1e30 - finite) = 0
      mrow[r] = mnew;
      float ps = 0.f;
#pragma unroll
      for (int ct = 0; ct < 8; ++ct) {
        pv[ct][r] = __expf(pv[ct][r] - mnew);
        ps += pv[ct][r];
      }
      ps += __shfl_xor(ps, 1, 64);
      ps += __shfl_xor(ps, 2, 64);
      ps += __shfl_xor(ps, 4, 64);
      ps += __shfl_xor(ps, 8, 64);
      lsum[r] = lsum[r] * corr[r] + ps;
    }
#pragma unroll
    for (int n = 0; n < 4; ++n)
#pragma unroll
      for (int r = 0; r < 4; ++r) oacc[n][r] *= corr[r];
    // P (16x128) -> LDS bf16, byte XOR-swizzle within 256B rows (G4)
#pragma unroll
    for (int ct = 0; ct < 8; ++ct) {
#pragma unroll
      for (int r = 0; r < 4; ++r) {
        int row = g * 4 + r;
        int bo = (row << 8) + (((ct * 16 + lr) * 2) ^ ((row & 15) << 4));
        *(ushort*)((char*)Pw + bo) = f2bf(pv[ct][r]);
      }
    }
    // PV: A = P from LDS (swizzled read), B = V^T fragments from global
#pragma unroll
    for (int ks = 0; ks < 4; ++ks) {
      int ci = (ks * 4 + g) ^ lr;
      bf16x8 pa = *(const bf16x8*)((const char*)Pw + (lr << 8) + (ci << 4));
#pragma unroll
      for (int n = 0; n < 4; ++n) {
        bf16x8 vb = load_frag(Vp + (size_t)(n * 16 + lr) * 2048 + t0 + ks * 32 + g * 8);
        oacc[n] = __builtin_amdgcn_mfma_f32_16x16x32_bf16(pa, vb, oacc[n], 0, 0, 0);
      }
    }
  }
#pragma unroll
  for (int n = 0; n < 4; ++n) {
#pragma unroll
    for (int r = 0; r < 4; ++r) {
      int s = sq0 + g * 4 + r;
      int col = h * 64 + n * 16 + lr;
      float v = oacc[n][r] / lsum[r];
      aout[(size_t)(b * 2048 + s) * 1024 + col] = f2bf(v);
    }
  }
}

// ---------------- launch ----------------
// ws layout (needs 72 MiB):
//   [0,16M)   xb  : x as bf16 [8192][1024]    (reused as attn-out after QKV)
//   [16,18M)  WqT  [18,20M) WkT  [20,22M) WvT  [22,24M) WoT   (bf16 [N][K])
//   [24,40M)  Qb [B,H,S,D] bf16
//   [40,56M)  Kb [B,H,S,D] bf16
//   [56,72M)  Vt [B,H,D,S] bf16
extern "C" void kernel_launch(void* const* d_in, const int* in_sizes, int n_in,
                              void* d_out, int out_size, void* d_ws, size_t ws_size,
                              hipStream_t stream) {
  const float* x  = (const float*)d_in[0];
  const float* Wq = (const float*)d_in[1];
  const float* bq = (const float*)d_in[2];
  const float* Wk = (const float*)d_in[3];
  const float* bk = (const float*)d_in[4];
  const float* Wv = (const float*)d_in[5];
  const float* bv = (const float*)d_in[6];
  const float* Wo = (const float*)d_in[7];
  const float* bo = (const float*)d_in[8];
  char* wsb = (char*)d_ws;
  ushort* xb   = (ushort*)(wsb);
  ushort* WqT  = (ushort*)(wsb + (16u << 20));
  ushort* WkT  = (ushort*)(wsb + (18u << 20));
  ushort* WvT  = (ushort*)(wsb + (20u << 20));
  ushort* WoT  = (ushort*)(wsb + (22u << 20));
  ushort* Qb   = (ushort*)(wsb + (24u << 20));
  ushort* Kb   = (ushort*)(wsb + (40u << 20));
  ushort* Vtb  = (ushort*)(wsb + (56u << 20));
  ushort* aout = xb;  // xb dead after the V projection

  k_convert_x<<<8192, 256, 0, stream>>>(x, xb);
  k_transpose_w<<<256, 256, 0, stream>>>(Wq, WqT);
  k_transpose_w<<<256, 256, 0, stream>>>(Wk, WkT);
  k_transpose_w<<<256, 256, 0, stream>>>(Wv, WvT);
  k_transpose_w<<<256, 256, 0, stream>>>(Wo, WoT);
  k_gemm<1><<<512, 256, 0, stream>>>(xb, WqT, bq, (void*)Qb);
  k_gemm<1><<<512, 256, 0, stream>>>(xb, WkT, bk, (void*)Kb);
  k_gemm<2><<<512, 256, 0, stream>>>(xb, WvT, bv, (void*)Vtb);
  k_attn<<<2048, 256, 0, stream>>>(Qb, Kb, Vtb, aout);
  k_gemm<0><<<512, 256, 0, stream>>>(aout, WoT, bo, d_out);
}

// Round 2
// 381.120 us; speedup vs baseline: 1.7299x; 1.7299x over previous
//
#include <hip/hip_runtime.h>

#define DI __device__ __forceinline__

typedef __bf16 bf16x8 __attribute__((ext_vector_type(8)));
typedef float f32x4 __attribute__((ext_vector_type(4)));

DI ushort f2bf(float f) {
  unsigned u = __builtin_bit_cast(unsigned, f);
  unsigned r = (u + 0x7FFFu + ((u >> 16) & 1u)) >> 16;
  return (ushort)r;
}

DI void gload_lds16(const void* g, void* l) {
  __builtin_amdgcn_global_load_lds(
      (const __attribute__((address_space(1))) unsigned*)g,
      (__attribute__((address_space(3))) unsigned*)l, 16, 0, 0);
}

DI bf16x8 load_frag(const ushort* p) { return *(const bf16x8*)p; }

// ---------------- convert x (f32 -> bf16), 4 elems/thread ----------------
__global__ __launch_bounds__(256) void k_convert_x(const float* __restrict__ x,
                                                   ushort* __restrict__ xb) {
  int i = (blockIdx.x * 256 + threadIdx.x) * 4;
  float4 v = *(const float4*)(x + i);
  ushort4 o;
  o.x = f2bf(v.x); o.y = f2bf(v.y); o.z = f2bf(v.z); o.w = f2bf(v.w);
  *(ushort4*)(xb + i) = o;
}

// ------- transpose-convert W[k][n] f32 -> Wt[n][k] bf16 (1024x1024) -------
__global__ __launch_bounds__(256) void k_transpose_w(const float* __restrict__ W,
                                                     ushort* __restrict__ Wt) {
  __shared__ float tile[64][65];
  int k0 = (blockIdx.x & 15) << 6;
  int n0 = (blockIdx.x >> 4) << 6;
  int c = threadIdx.x & 63;
  int r0 = threadIdx.x >> 6;
#pragma unroll
  for (int i = 0; i < 16; ++i) {
    int r = i * 4 + r0;
    tile[r][c] = W[(k0 + r) * 1024 + n0 + c];
  }
  __syncthreads();
#pragma unroll
  for (int i = 0; i < 16; ++i) {
    int nn = i * 4 + r0;
    Wt[(n0 + nn) * 1024 + k0 + c] = f2bf(tile[c][nn]);
  }
}

// ---------------- GEMM: C[M=8192,N=1024] = A[M,K=1024] @ Bt[N,K]^T + bias ----------------
// MODE 0: fp32 row-major out.  MODE 1: bf16 -> [B,H,S,D].  MODE 2: bf16 -> [B,H,D,S].
template <int MODE>
__global__ __launch_bounds__(256, 2) void k_gemm(const ushort* __restrict__ A,
                                                 const ushort* __restrict__ Bt,
                                                 const float* __restrict__ bias,
                                                 void* __restrict__ out) {
  __shared__ ushort Asm[8192];  // [128 rows][64 k] bf16, swizzled
  __shared__ ushort Bsm[8192];
  int L = blockIdx.x;
  int wg = (L & 7) * 64 + (L >> 3);  // bijective XCD swizzle (512 % 8 == 0)
  int brow = wg >> 3;                // 0..63
  int bcol = wg & 7;                 // 0..7
  int tid = threadIdx.x;
  int w = tid >> 6, lane = tid & 63;
  int g = lane >> 4, lr = lane & 15;
  int wr = w >> 1, wc = w & 1;
  const char* Abase = (const char*)(A + (size_t)brow * 128 * 1024);
  const char* Bbase = (const char*)(Bt + (size_t)bcol * 128 * 1024);
  f32x4 acc[4][4] = {};
  for (int kt = 0; kt < 16; ++kt) {
    int k0b = kt * 128;  // byte offset along K
#pragma unroll
    for (int i = 0; i < 4; ++i) {
      int j = w * 4 + i;             // 16 slots of 1 KiB
      int fo = j * 1024 + lane * 16; // linear LDS dest byte
      int row = fo >> 7;
      int cis = ((fo >> 4) & 7) ^ (row & 7);  // inverse-swizzled source chunk
      long srcoff = (long)row * 2048 + k0b + cis * 16;
      gload_lds16(Abase + srcoff, (char*)Asm + j * 1024);
      gload_lds16(Bbase + srcoff, (char*)Bsm + j * 1024);
    }
    __syncthreads();
#pragma unroll
    for (int ks = 0; ks < 2; ++ks) {
      bf16x8 af[4], bfr[4];
#pragma unroll
      for (int m = 0; m < 4; ++m) {
        int row = wr * 64 + m * 16 + lr;
        int ci = (ks * 4 + g) ^ (row & 7);
        af[m] = *(const bf16x8*)((const char*)Asm + row * 128 + ci * 16);
      }
#pragma unroll
      for (int n = 0; n < 4; ++n) {
        int row = wc * 64 + n * 16 + lr;
        int ci = (ks * 4 + g) ^ (row & 7);
        bfr[n] = *(const bf16x8*)((const char*)Bsm + row * 128 + ci * 16);
      }
#pragma unroll
      for (int m = 0; m < 4; ++m)
#pragma unroll
        for (int n = 0; n < 4; ++n)
          acc[m][n] = __builtin_amdgcn_mfma_f32_16x16x32_bf16(af[m], bfr[n], acc[m][n], 0, 0, 0);
    }
    __syncthreads();
  }
#pragma unroll
  for (int m = 0; m < 4; ++m) {
#pragma unroll
    for (int n = 0; n < 4; ++n) {
      int Cc = bcol * 128 + wc * 64 + n * 16 + lr;
      float bv = bias[Cc];
#pragma unroll
      for (int r = 0; r < 4; ++r) {
        int R = brow * 128 + wr * 64 + m * 16 + g * 4 + r;
        float v = acc[m][n][r] + bv;
        if (MODE == 0) {
          ((float*)out)[(size_t)R * 1024 + Cc] = v;
        } else if (MODE == 1) {
          int b = R >> 11, s = R & 2047, h = Cc >> 6, d = Cc & 63;
          ((ushort*)out)[(((size_t)(b * 16 + h) * 2048 + s) << 6) + d] = f2bf(v);
        } else {
          int b = R >> 11, s = R & 2047, h = Cc >> 6, d = Cc & 63;
          ((ushort*)out)[(((size_t)(b * 16 + h) * 64 + d) << 11) + s] = f2bf(v);
        }
      }
    }
  }
}

// ---------------- flash attention (LDS-staged, double-buffered) ----------------
// K tile [128][64] and V^T tile [64][128] staged via global_load_lds w16,
// XOR-swizzled (linear LDS dest + inverse-swizzled source + swizzled read, G21).
// m97-style pipeline: stage tile t+1, compute tile t, one __syncthreads per tile.
DI void stage_kv(const char* Kp, const char* Vp, char* KsmB, char* VsmB,
                 int t0, int w, int lane) {
#pragma unroll
  for (int i = 0; i < 4; ++i) {
    int j = w * 4 + i;               // 16 slots of 1 KiB
    int fo = j * 1024 + lane * 16;   // linear LDS dest byte
    // K tile: rows of 128B (8 chunks); swizzle chunk ^= row&7
    int krow = fo >> 7;
    int kch = ((fo >> 4) & 7) ^ (krow & 7);
    gload_lds16(Kp + (size_t)(t0 + krow) * 128 + kch * 16, KsmB + j * 1024);
    // V^T tile: rows of 256B (16 chunks); swizzle chunk ^= row&15
    int vrow = fo >> 8;
    int vch = ((fo >> 4) & 15) ^ (vrow & 15);
    gload_lds16(Vp + (size_t)vrow * 4096 + (size_t)t0 * 2 + vch * 16, VsmB + j * 1024);
  }
}

__global__ __launch_bounds__(256, 2) void k_attn(const ushort* __restrict__ Qb,
                                                 const ushort* __restrict__ Kb,
                                                 const ushort* __restrict__ Vt,
                                                 ushort* __restrict__ aout) {
  __shared__ ushort Ksm[2][8192];  // [buf][128 rows][64] bf16, swizzled
  __shared__ ushort Vsm[2][8192];  // [buf][64 rows][128] bf16, swizzled
  __shared__ ushort Psm[4][2048];  // per-wave 16x128 bf16, swizzled
  int L = blockIdx.x;
  int mm = L >> 3;
  int bh = (L & 7) * 8 + (mm >> 5);  // all 32 q-tiles of a bh on one XCD
  int qt = mm & 31;
  int b = bh >> 4, h = bh & 15;
  int tid = threadIdx.x;
  int w = tid >> 6, lane = tid & 63, g = lane >> 4, lr = lane & 15;
  const ushort* Qp = Qb + (size_t)bh * 2048 * 64;
  const char* Kp = (const char*)(Kb + (size_t)bh * 2048 * 64);
  const char* Vp = (const char*)(Vt + (size_t)bh * 64 * 2048);
  int sq0 = qt * 64 + w * 16;
  bf16x8 qa[2];
#pragma unroll
  for (int ks = 0; ks < 2; ++ks)
    qa[ks] = load_frag(Qp + (sq0 + lr) * 64 + ks * 32 + g * 8);
  float mrow[4], lsum[4];
  f32x4 oacc[4] = {};
#pragma unroll
  for (int r = 0; r < 4; ++r) { mrow[r] = -1e30f; lsum[r] = 0.f; }
  char* Pw = (char*)&Psm[w][0];
  const float sc = 0.125f * 1.44269504089f;  // 1/sqrt(64) * log2(e); exp via exp2

  stage_kv(Kp, Vp, (char*)Ksm[0], (char*)Vsm[0], 0, w, lane);
  __syncthreads();
  int cur = 0;
  for (int t = 0; t < 16; ++t) {
    if (t < 15)
      stage_kv(Kp, Vp, (char*)Ksm[cur ^ 1], (char*)Vsm[cur ^ 1], (t + 1) * 128, w, lane);
    const char* Kc = (const char*)Ksm[cur];
    const char* Vc = (const char*)Vsm[cur];
    // ---- QK^T from LDS ----
    f32x4 sacc[8] = {};
#pragma unroll
    for (int ct = 0; ct < 8; ++ct) {
#pragma unroll
      for (int ks = 0; ks < 2; ++ks) {
        int row = ct * 16 + lr;
        int ci = (ks * 4 + g) ^ (row & 7);
        bf16x8 kb = *(const bf16x8*)(Kc + row * 128 + ci * 16);
        sacc[ct] = __builtin_amdgcn_mfma_f32_16x16x32_bf16(qa[ks], kb, sacc[ct], 0, 0, 0);
      }
    }
    // ---- online softmax (log2 domain) ----
    float pv[8][4];
#pragma unroll
    for (int ct = 0; ct < 8; ++ct)
#pragma unroll
      for (int r = 0; r < 4; ++r) pv[ct][r] = sacc[ct][r] * sc;
    float corr[4];
#pragma unroll
    for (int r = 0; r < 4; ++r) {
      float pm = pv[0][r];
#pragma unroll
      for (int ct = 1; ct < 8; ++ct) pm = fmaxf(pm, pv[ct][r]);
      pm = fmaxf(pm, __shfl_xor(pm, 1, 64));
      pm = fmaxf(pm, __shfl_xor(pm, 2, 64));
      pm = fmaxf(pm, __shfl_xor(pm, 4, 64));
      pm = fmaxf(pm, __shfl_xor(pm, 8, 64));
      float mnew = fmaxf(mrow[r], pm);
      corr[r] = __builtin_amdgcn_exp2f(mrow[r] - mnew);
      mrow[r] = mnew;
      float ps = 0.f;
#pragma unroll
      for (int ct = 0; ct < 8; ++ct) {
        pv[ct][r] = __builtin_amdgcn_exp2f(pv[ct][r] - mnew);
        ps += pv[ct][r];
      }
      ps += __shfl_xor(ps, 1, 64);
      ps += __shfl_xor(ps, 2, 64);
      ps += __shfl_xor(ps, 4, 64);
      ps += __shfl_xor(ps, 8, 64);
      lsum[r] = lsum[r] * corr[r] + ps;
    }
#pragma unroll
    for (int n = 0; n < 4; ++n)
#pragma unroll
      for (int r = 0; r < 4; ++r) oacc[n][r] *= corr[r];
    // ---- P (16x128) -> per-wave LDS, swizzled ----
#pragma unroll
    for (int ct = 0; ct < 8; ++ct) {
#pragma unroll
      for (int r = 0; r < 4; ++r) {
        int row = g * 4 + r;
        int bo = (row << 8) + (((ct * 16 + lr) * 2) ^ ((row & 15) << 4));
        *(ushort*)(Pw + bo) = f2bf(pv[ct][r]);
      }
    }
    // ---- PV: A = P (LDS), B = V^T (LDS) ----
#pragma unroll
    for (int ks = 0; ks < 4; ++ks) {
      int ci = (ks * 4 + g) ^ lr;
      bf16x8 pa = *(const bf16x8*)(Pw + (lr << 8) + (ci << 4));
#pragma unroll
      for (int n = 0; n < 4; ++n) {
        int row = n * 16 + lr;
        int vi = (ks * 4 + g) ^ (row & 15);
        bf16x8 vb = *(const bf16x8*)(Vc + row * 256 + vi * 16);
        oacc[n] = __builtin_amdgcn_mfma_f32_16x16x32_bf16(pa, vb, oacc[n], 0, 0, 0);
      }
    }
    __syncthreads();
    cur ^= 1;
  }
#pragma unroll
  for (int n = 0; n < 4; ++n) {
#pragma unroll
    for (int r = 0; r < 4; ++r) {
      int s = sq0 + g * 4 + r;
      int col = h * 64 + n * 16 + lr;
      float v = oacc[n][r] / lsum[r];
      aout[(size_t)(b * 2048 + s) * 1024 + col] = f2bf(v);
    }
  }
}

// ---------------- launch ----------------
// ws layout (needs 72 MiB):
//   [0,16M)   xb  : x as bf16 [8192][1024]    (reused as attn-out after QKV)
//   [16,18M)  WqT  [18,20M) WkT  [20,22M) WvT  [22,24M) WoT   (bf16 [N][K])
//   [24,40M)  Qb [B,H,S,D] bf16
//   [40,56M)  Kb [B,H,S,D] bf16
//   [56,72M)  Vt [B,H,D,S] bf16
extern "C" void kernel_launch(void* const* d_in, const int* in_sizes, int n_in,
                              void* d_out, int out_size, void* d_ws, size_t ws_size,
                              hipStream_t stream) {
  const float* x  = (const float*)d_in[0];
  const float* Wq = (const float*)d_in[1];
  const float* bq = (const float*)d_in[2];
  const float* Wk = (const float*)d_in[3];
  const float* bk = (const float*)d_in[4];
  const float* Wv = (const float*)d_in[5];
  const float* bv = (const float*)d_in[6];
  const float* Wo = (const float*)d_in[7];
  const float* bo = (const float*)d_in[8];
  char* wsb = (char*)d_ws;
  ushort* xb   = (ushort*)(wsb);
  ushort* WqT  = (ushort*)(wsb + (16u << 20));
  ushort* WkT  = (ushort*)(wsb + (18u << 20));
  ushort* WvT  = (ushort*)(wsb + (20u << 20));
  ushort* WoT  = (ushort*)(wsb + (22u << 20));
  ushort* Qb   = (ushort*)(wsb + (24u << 20));
  ushort* Kb   = (ushort*)(wsb + (40u << 20));
  ushort* Vtb  = (ushort*)(wsb + (56u << 20));
  ushort* aout = xb;  // xb dead after the V projection

  k_convert_x<<<8192, 256, 0, stream>>>(x, xb);
  k_transpose_w<<<256, 256, 0, stream>>>(Wq, WqT);
  k_transpose_w<<<256, 256, 0, stream>>>(Wk, WkT);
  k_transpose_w<<<256, 256, 0, stream>>>(Wv, WvT);
  k_transpose_w<<<256, 256, 0, stream>>>(Wo, WoT);
  k_gemm<1><<<512, 256, 0, stream>>>(xb, WqT, bq, (void*)Qb);
  k_gemm<1><<<512, 256, 0, stream>>>(xb, WkT, bk, (void*)Kb);
  k_gemm<2><<<512, 256, 0, stream>>>(xb, WvT, bv, (void*)Vtb);
  k_attn<<<2048, 256, 0, stream>>>(Qb, Kb, Vtb, aout);
  k_gemm<0><<<512, 256, 0, stream>>>(aout, WoT, bo, d_out);
}

// Round 3
// 294.459 us; speedup vs baseline: 2.2390x; 1.2943x over previous
//
#include <hip/hip_runtime.h>

#define DI __device__ __forceinline__

typedef __bf16 bf16x8 __attribute__((ext_vector_type(8)));
typedef float f32x4 __attribute__((ext_vector_type(4)));
typedef float f32x16 __attribute__((ext_vector_type(16)));
typedef unsigned u32;
typedef u32 u32x2v __attribute__((ext_vector_type(2)));
typedef u32 u32x4v __attribute__((ext_vector_type(4)));

DI ushort f2bf(float f) {
  unsigned u = __builtin_bit_cast(unsigned, f);
  unsigned r = (u + 0x7FFFu + ((u >> 16) & 1u)) >> 16;
  return (ushort)r;
}

DI void gload_lds16(const void* g, void* l) {
  __builtin_amdgcn_global_load_lds(
      (const __attribute__((address_space(1))) unsigned*)g,
      (__attribute__((address_space(3))) unsigned*)l, 16, 0, 0);
}

DI bf16x8 load_frag(const ushort* p) { return *(const bf16x8*)p; }

DI u32 cvtpk(float lo, float hi) {
  u32 r;
  asm("v_cvt_pk_bf16_f32 %0, %1, %2" : "=v"(r) : "v"(lo), "v"(hi));
  return r;
}

#if defined(__has_builtin)
#if __has_builtin(__builtin_amdgcn_permlane32_swap)
#define HAVE_PLSWAP 1
#endif
#endif

// swap A.hi <-> B.lo: returns {[A.lo|B.lo], [A.hi|B.hi]}
DI u32x2v permswap(u32 a, u32 b) {
#ifdef HAVE_PLSWAP
  return __builtin_amdgcn_permlane32_swap(a, b, false, false);
#else
  int hi = (threadIdx.x >> 5) & 1;
  u32 bl = __shfl_xor(b, 32, 64);
  u32 ah = __shfl_xor(a, 32, 64);
  u32x2v r;
  r[0] = hi ? bl : a;
  r[1] = hi ? b : ah;
  return r;
#endif
}

DI f32x16 mfma32(bf16x8 a, bf16x8 b, f32x16 c) {
  return __builtin_amdgcn_mfma_f32_32x32x16_bf16(a, b, c, 0, 0, 0);
}

// ---------------- convert x (f32 -> bf16), 4 elems/thread ----------------
__global__ __launch_bounds__(256) void k_convert_x(const float* __restrict__ x,
                                                   ushort* __restrict__ xb) {
  int i = (blockIdx.x * 256 + threadIdx.x) * 4;
  float4 v = *(const float4*)(x + i);
  ushort4 o;
  o.x = f2bf(v.x); o.y = f2bf(v.y); o.z = f2bf(v.z); o.w = f2bf(v.w);
  *(ushort4*)(xb + i) = o;
}

// ------- transpose-convert W[k][n] f32 -> Wt[n][k] bf16 (1024x1024) -------
__global__ __launch_bounds__(256) void k_transpose_w(const float* __restrict__ W,
                                                     ushort* __restrict__ Wt) {
  __shared__ float tile[64][65];
  int k0 = (blockIdx.x & 15) << 6;
  int n0 = (blockIdx.x >> 4) << 6;
  int c = threadIdx.x & 63;
  int r0 = threadIdx.x >> 6;
#pragma unroll
  for (int i = 0; i < 16; ++i) {
    int r = i * 4 + r0;
    tile[r][c] = W[(k0 + r) * 1024 + n0 + c];
  }
  __syncthreads();
#pragma unroll
  for (int i = 0; i < 16; ++i) {
    int nn = i * 4 + r0;
    Wt[(n0 + nn) * 1024 + k0 + c] = f2bf(tile[c][nn]);
  }
}

// ---------------- GEMM: C[M=8192,N=1024] = A[M,K=1024] @ Bt[N,K]^T + bias ----------------
// MODE 0: fp32 row-major out.  MODE 1: bf16 -> [B,H,S,D].  MODE 2: bf16 -> [B,H,D,S].
template <int MODE>
__global__ __launch_bounds__(256, 2) void k_gemm(const ushort* __restrict__ A,
                                                 const ushort* __restrict__ Bt,
                                                 const float* __restrict__ bias,
                                                 void* __restrict__ out) {
  __shared__ ushort Asm[8192];  // [128 rows][64 k] bf16, swizzled
  __shared__ ushort Bsm[8192];
  int L = blockIdx.x;
  int wg = (L & 7) * 64 + (L >> 3);  // bijective XCD swizzle (512 % 8 == 0)
  int brow = wg >> 3;                // 0..63
  int bcol = wg & 7;                 // 0..7
  int tid = threadIdx.x;
  int w = tid >> 6, lane = tid & 63;
  int g = lane >> 4, lr = lane & 15;
  int wr = w >> 1, wc = w & 1;
  const char* Abase = (const char*)(A + (size_t)brow * 128 * 1024);
  const char* Bbase = (const char*)(Bt + (size_t)bcol * 128 * 1024);
  f32x4 acc[4][4] = {};
  for (int kt = 0; kt < 16; ++kt) {
    int k0b = kt * 128;  // byte offset along K
#pragma unroll
    for (int i = 0; i < 4; ++i) {
      int j = w * 4 + i;             // 16 slots of 1 KiB
      int fo = j * 1024 + lane * 16; // linear LDS dest byte
      int row = fo >> 7;
      int cis = ((fo >> 4) & 7) ^ (row & 7);  // inverse-swizzled source chunk
      long srcoff = (long)row * 2048 + k0b + cis * 16;
      gload_lds16(Abase + srcoff, (char*)Asm + j * 1024);
      gload_lds16(Bbase + srcoff, (char*)Bsm + j * 1024);
    }
    __syncthreads();
#pragma unroll
    for (int ks = 0; ks < 2; ++ks) {
      bf16x8 af[4], bfr[4];
#pragma unroll
      for (int m = 0; m < 4; ++m) {
        int row = wr * 64 + m * 16 + lr;
        int ci = (ks * 4 + g) ^ (row & 7);
        af[m] = *(const bf16x8*)((const char*)Asm + row * 128 + ci * 16);
      }
#pragma unroll
      for (int n = 0; n < 4; ++n) {
        int row = wc * 64 + n * 16 + lr;
        int ci = (ks * 4 + g) ^ (row & 7);
        bfr[n] = *(const bf16x8*)((const char*)Bsm + row * 128 + ci * 16);
      }
#pragma unroll
      for (int m = 0; m < 4; ++m)
#pragma unroll
        for (int n = 0; n < 4; ++n)
          acc[m][n] = __builtin_amdgcn_mfma_f32_16x16x32_bf16(af[m], bfr[n], acc[m][n], 0, 0, 0);
    }
    __syncthreads();
  }
#pragma unroll
  for (int m = 0; m < 4; ++m) {
#pragma unroll
    for (int n = 0; n < 4; ++n) {
      int Cc = bcol * 128 + wc * 64 + n * 16 + lr;
      float bv = bias[Cc];
#pragma unroll
      for (int r = 0; r < 4; ++r) {
        int R = brow * 128 + wr * 64 + m * 16 + g * 4 + r;
        float v = acc[m][n][r] + bv;
        if (MODE == 0) {
          ((float*)out)[(size_t)R * 1024 + Cc] = v;
        } else if (MODE == 1) {
          int b = R >> 11, s = R & 2047, h = Cc >> 6, d = Cc & 63;
          ((ushort*)out)[(((size_t)(b * 16 + h) * 2048 + s) << 6) + d] = f2bf(v);
        } else {
          int b = R >> 11, s = R & 2047, h = Cc >> 6, d = Cc & 63;
          ((ushort*)out)[(((size_t)(b * 16 + h) * 64 + d) << 11) + s] = f2bf(v);
        }
      }
    }
  }
}

// ---------------- flash attention v3: swapped-QK 32x32, in-register softmax --------
// Block = (b,h) x 2 q-tiles of 128; 4 warps x 32 q-rows. KVBLK=64.
// S^T[kv][q] = K·Q^T via mfma_32x32x16(A=K-frag, B=Q-frag): lane owns column
// q=lane&31; kv lives in regs [(reg&3)+8*(reg>>2)+4*hi] -> softmax is in-lane
// tree + one cross-half exchange. P^T -> PV B-operand via cvt_pk + permlane32_swap
// (T12). out^T[d][q] = V^T·P^T with A=V^T-frag. K/V tiles [64][64] bf16 in LDS,
// XOR-swizzled (G21), double-buffered, one barrier per tile.
DI void stage2(const char* Kp, const char* Vp, char* Kd, char* Vd, int t0,
               int w, int lane) {
#pragma unroll
  for (int i = 0; i < 2; ++i) {
    int j = w * 2 + i;               // 8 slots of 1 KiB
    int fo = j * 1024 + lane * 16;   // linear LDS dest byte
    int row = fo >> 7;               // 0..63
    int ch = ((fo >> 4) & 7) ^ (row & 7);
    gload_lds16(Kp + (size_t)(t0 + row) * 128 + ch * 16, Kd + j * 1024);
    gload_lds16(Vp + (size_t)row * 4096 + (size_t)t0 * 2 + ch * 16, Vd + j * 1024);
  }
}

#define PACKP(pp, base, dst)                                \
  {                                                         \
    u32 a0 = cvtpk(pp[(base) + 0], pp[(base) + 1]);         \
    u32 b0 = cvtpk(pp[(base) + 4], pp[(base) + 5]);         \
    u32 a1 = cvtpk(pp[(base) + 2], pp[(base) + 3]);         \
    u32 b1 = cvtpk(pp[(base) + 6], pp[(base) + 7]);         \
    u32x2v r0 = permswap(a0, b0);                           \
    u32x2v r1 = permswap(a1, b1);                           \
    u32x4v f;                                               \
    f.x = r0.x; f.y = r1.x; f.z = r0.y; f.w = r1.y;         \
    dst = __builtin_bit_cast(bf16x8, f);                    \
  }

__global__ __launch_bounds__(256, 3) void k_attn(const ushort* __restrict__ Qb,
                                                 const ushort* __restrict__ Kb,
                                                 const ushort* __restrict__ Vt,
                                                 ushort* __restrict__ aout) {
  __shared__ ushort Ksm[2][4096];  // [buf][64 kv][64 d] bf16, swizzled
  __shared__ ushort Vsm[2][4096];  // [buf][64 d][64 kv] bf16, swizzled
  int L = blockIdx.x;              // 512 blocks: 8 xcd x 8 bh x 8 qpair
  int xcd = L & 7, idx = L >> 3;
  int bh = xcd * 8 + (idx >> 3);
  int qpair = idx & 7;
  int b = bh >> 4, h = bh & 15;
  int tid = threadIdx.x;
  int w = tid >> 6, lane = tid & 63, l31 = lane & 31, hi = lane >> 5;
  const ushort* Qp = Qb + (size_t)bh * 2048 * 64;
  const char* Kp = (const char*)(Kb + (size_t)bh * 2048 * 64);
  const char* Vp = (const char*)(Vt + (size_t)bh * 64 * 2048);
  const float sc = 0.18033688f;  // (1/8) * log2(e)

  for (int qq = 0; qq < 2; ++qq) {
    int q0 = (qpair * 2 + qq) * 128 + w * 32;
    bf16x8 qf[4];
#pragma unroll
    for (int ks = 0; ks < 4; ++ks)
      qf[ks] = load_frag(Qp + (q0 + l31) * 64 + ks * 16 + hi * 8);
    f32x16 o0 = {}, o1 = {};
    float m_s = -1e30f, lsum = 0.f;

    stage2(Kp, Vp, (char*)Ksm[0], (char*)Vsm[0], 0, w, lane);
    __syncthreads();
    int cur = 0;
#pragma unroll 2
    for (int t = 0; t < 32; ++t) {
      if (t < 31)
        stage2(Kp, Vp, (char*)Ksm[cur ^ 1], (char*)Vsm[cur ^ 1], (t + 1) * 64, w, lane);
      const char* Kc = (const char*)Ksm[cur];
      const char* Vc = (const char*)Vsm[cur];
      // ---- QK^T (swapped): S^T[kv][q] ----
      f32x16 s0 = {}, s1 = {};
#pragma unroll
      for (int ks = 0; ks < 4; ++ks) {
        int ci = ((ks * 2 + hi) ^ (l31 & 7)) << 4;
        bf16x8 ka0 = *(const bf16x8*)(Kc + l31 * 128 + ci);
        bf16x8 ka1 = *(const bf16x8*)(Kc + (32 + l31) * 128 + ci);
        s0 = mfma32(ka0, qf[ks], s0);
        s1 = mfma32(ka1, qf[ks], s1);
      }
      // ---- in-register online softmax (log2 domain, scale folded) ----
      float mx[16];
#pragma unroll
      for (int i = 0; i < 16; ++i) mx[i] = fmaxf(s0[i], s1[i]);
#pragma unroll
      for (int st = 8; st >= 1; st >>= 1)
#pragma unroll
        for (int i = 0; i < st; ++i) mx[i] = fmaxf(mx[i], mx[i + st]);
      float pm = fmaxf(mx[0], __shfl_xor(mx[0], 32, 64)) * sc;
      if (__ballot(pm > m_s + 8.f)) {  // T13 defer-max
        float mnew = fmaxf(m_s, pm);
        float corr = __builtin_amdgcn_exp2f(m_s - mnew);
        m_s = mnew;
#pragma unroll
        for (int i = 0; i < 16; ++i) { o0[i] *= corr; o1[i] *= corr; }
        lsum *= corr;
      }
      float p0[16], p1[16];
#pragma unroll
      for (int i = 0; i < 16; ++i) {
        p0[i] = __builtin_amdgcn_exp2f(__builtin_fmaf(s0[i], sc, -m_s));
        p1[i] = __builtin_amdgcn_exp2f(__builtin_fmaf(s1[i], sc, -m_s));
      }
      float sm[16];
#pragma unroll
      for (int i = 0; i < 16; ++i) sm[i] = p0[i] + p1[i];
#pragma unroll
      for (int st = 8; st >= 1; st >>= 1)
#pragma unroll
        for (int i = 0; i < st; ++i) sm[i] += sm[i + st];
      lsum += sm[0] + __shfl_xor(sm[0], 32, 64);
      // ---- P^T -> B-fragments (in-register, T12) ----
      bf16x8 pb0, pb1, pb2, pb3;
      PACKP(p0, 0, pb0);
      PACKP(p0, 8, pb1);
      PACKP(p1, 0, pb2);
      PACKP(p1, 8, pb3);
      // ---- PV: out^T[d][q] += V^T · P^T ----
#pragma unroll
      for (int ks = 0; ks < 4; ++ks) {
        int ci = ((ks * 2 + hi) ^ (l31 & 7)) << 4;
        bf16x8 va0 = *(const bf16x8*)(Vc + l31 * 128 + ci);
        bf16x8 va1 = *(const bf16x8*)(Vc + (32 + l31) * 128 + ci);
        bf16x8 pb = (ks == 0) ? pb0 : (ks == 1) ? pb1 : (ks == 2) ? pb2 : pb3;
        o0 = mfma32(va0, pb, o0);
        o1 = mfma32(va1, pb, o1);
      }
      __syncthreads();
      cur ^= 1;
    }
    // ---- epilogue: lane owns row s = q0 + l31; d = (reg&3)+8*(reg>>2)+4*hi ----
    float rl = 1.f / lsum;
    ushort* orow = aout + ((size_t)b * 2048 + q0 + l31) * 1024 + h * 64;
#pragma unroll
    for (int r = 0; r < 8; ++r) {
      int d0 = ((2 * r) & 3) + 8 * ((2 * r) >> 2) + 4 * hi;
      *(u32*)(orow + d0) = cvtpk(o0[2 * r] * rl, o0[2 * r + 1] * rl);
      *(u32*)(orow + 32 + d0) = cvtpk(o1[2 * r] * rl, o1[2 * r + 1] * rl);
    }
  }
}

// ---------------- launch ----------------
// ws layout (needs 72 MiB):
//   [0,16M)   xb  : x as bf16 [8192][1024]    (reused as attn-out after QKV)
//   [16,18M)  WqT  [18,20M) WkT  [20,22M) WvT  [22,24M) WoT   (bf16 [N][K])
//   [24,40M)  Qb [B,H,S,D] bf16
//   [40,56M)  Kb [B,H,S,D] bf16
//   [56,72M)  Vt [B,H,D,S] bf16
extern "C" void kernel_launch(void* const* d_in, const int* in_sizes, int n_in,
                              void* d_out, int out_size, void* d_ws, size_t ws_size,
                              hipStream_t stream) {
  const float* x  = (const float*)d_in[0];
  const float* Wq = (const float*)d_in[1];
  const float* bq = (const float*)d_in[2];
  const float* Wk = (const float*)d_in[3];
  const float* bk = (const float*)d_in[4];
  const float* Wv = (const float*)d_in[5];
  const float* bv = (const float*)d_in[6];
  const float* Wo = (const float*)d_in[7];
  const float* bo = (const float*)d_in[8];
  char* wsb = (char*)d_ws;
  ushort* xb   = (ushort*)(wsb);
  ushort* WqT  = (ushort*)(wsb + (16u << 20));
  ushort* WkT  = (ushort*)(wsb + (18u << 20));
  ushort* WvT  = (ushort*)(wsb + (20u << 20));
  ushort* WoT  = (ushort*)(wsb + (22u << 20));
  ushort* Qb   = (ushort*)(wsb + (24u << 20));
  ushort* Kb   = (ushort*)(wsb + (40u << 20));
  ushort* Vtb  = (ushort*)(wsb + (56u << 20));
  ushort* aout = xb;  // xb dead after the V projection

  k_convert_x<<<8192, 256, 0, stream>>>(x, xb);
  k_transpose_w<<<256, 256, 0, stream>>>(Wq, WqT);
  k_transpose_w<<<256, 256, 0, stream>>>(Wk, WkT);
  k_transpose_w<<<256, 256, 0, stream>>>(Wv, WvT);
  k_transpose_w<<<256, 256, 0, stream>>>(Wo, WoT);
  k_gemm<1><<<512, 256, 0, stream>>>(xb, WqT, bq, (void*)Qb);
  k_gemm<1><<<512, 256, 0, stream>>>(xb, WkT, bk, (void*)Kb);
  k_gemm<2><<<512, 256, 0, stream>>>(xb, WvT, bv, (void*)Vtb);
  k_attn<<<512, 256, 0, stream>>>(Qb, Kb, Vtb, aout);
  k_gemm<0><<<512, 256, 0, stream>>>(aout, WoT, bo, d_out);
}

// Round 4
// 289.634 us; speedup vs baseline: 2.2763x; 1.0167x over previous
//
#include <hip/hip_runtime.h>

#define DI __device__ __forceinline__

typedef __bf16 bf16x8 __attribute__((ext_vector_type(8)));
typedef float f32x4 __attribute__((ext_vector_type(4)));
typedef float f32x16 __attribute__((ext_vector_type(16)));
typedef unsigned u32;
typedef u32 u32x2v __attribute__((ext_vector_type(2)));
typedef u32 u32x4v __attribute__((ext_vector_type(4)));

DI ushort f2bf(float f) {
  unsigned u = __builtin_bit_cast(unsigned, f);
  unsigned r = (u + 0x7FFFu + ((u >> 16) & 1u)) >> 16;
  return (ushort)r;
}

DI void gload_lds16(const void* g, void* l) {
  __builtin_amdgcn_global_load_lds(
      (const __attribute__((address_space(1))) unsigned*)g,
      (__attribute__((address_space(3))) unsigned*)l, 16, 0, 0);
}

DI bf16x8 load_frag(const ushort* p) { return *(const bf16x8*)p; }

DI u32 cvtpk(float lo, float hi) {
  u32 r;
  asm("v_cvt_pk_bf16_f32 %0, %1, %2" : "=v"(r) : "v"(lo), "v"(hi));
  return r;
}

#if defined(__has_builtin)
#if __has_builtin(__builtin_amdgcn_permlane32_swap)
#define HAVE_PLSWAP 1
#endif
#endif

// swap A.hi <-> B.lo: returns {[A.lo|B.lo], [A.hi|B.hi]}
DI u32x2v permswap(u32 a, u32 b) {
#ifdef HAVE_PLSWAP
  return __builtin_amdgcn_permlane32_swap(a, b, false, false);
#else
  int hi = (threadIdx.x >> 5) & 1;
  u32 bl = __shfl_xor(b, 32, 64);
  u32 ah = __shfl_xor(a, 32, 64);
  u32x2v r;
  r[0] = hi ? bl : a;
  r[1] = hi ? b : ah;
  return r;
#endif
}

DI f32x16 mfma32(bf16x8 a, bf16x8 b, f32x16 c) {
  return __builtin_amdgcn_mfma_f32_32x32x16_bf16(a, b, c, 0, 0, 0);
}

// ---------------- convert x (f32 -> bf16), 4 elems/thread ----------------
__global__ __launch_bounds__(256) void k_convert_x(const float* __restrict__ x,
                                                   ushort* __restrict__ xb) {
  int i = (blockIdx.x * 256 + threadIdx.x) * 4;
  float4 v = *(const float4*)(x + i);
  ushort4 o;
  o.x = f2bf(v.x); o.y = f2bf(v.y); o.z = f2bf(v.z); o.w = f2bf(v.w);
  *(ushort4*)(xb + i) = o;
}

// --- fused transpose-convert of all 4 weights: W[k][n] f32 -> Wt[n][k] bf16 ---
__global__ __launch_bounds__(256) void k_transpose_w4(
    const float* __restrict__ W0, const float* __restrict__ W1,
    const float* __restrict__ W2, const float* __restrict__ W3,
    ushort* __restrict__ T0, ushort* __restrict__ T1,
    ushort* __restrict__ T2, ushort* __restrict__ T3) {
  __shared__ float tile[64][65];
  int which = blockIdx.x >> 8;
  int bt = blockIdx.x & 255;
  const float* W = which == 0 ? W0 : which == 1 ? W1 : which == 2 ? W2 : W3;
  ushort* Wt = which == 0 ? T0 : which == 1 ? T1 : which == 2 ? T2 : T3;
  int k0 = (bt & 15) << 6;
  int n0 = (bt >> 4) << 6;
  int c = threadIdx.x & 63;
  int r0 = threadIdx.x >> 6;
#pragma unroll
  for (int i = 0; i < 16; ++i) {
    int r = i * 4 + r0;
    tile[r][c] = W[(k0 + r) * 1024 + n0 + c];
  }
  __syncthreads();
#pragma unroll
  for (int i = 0; i < 16; ++i) {
    int nn = i * 4 + r0;
    Wt[(n0 + nn) * 1024 + k0 + c] = f2bf(tile[c][nn]);
  }
}

// ---------------- GEMM: C[M=8192,N=1024] = A[M,K=1024] @ Bt[N,K]^T + bias ----------------
// MODE 0: fp32 row-major out.  MODE 1: bf16 -> [B,H,S,D].  MODE 2: bf16 -> [B,H,D,S].
template <int MODE>
__global__ __launch_bounds__(256, 2) void k_gemm(const ushort* __restrict__ A,
                                                 const ushort* __restrict__ Bt,
                                                 const float* __restrict__ bias,
                                                 void* __restrict__ out) {
  __shared__ ushort Asm[8192];  // [128 rows][64 k] bf16, swizzled
  __shared__ ushort Bsm[8192];
  int L = blockIdx.x;
  int wg = (L & 7) * 64 + (L >> 3);  // bijective XCD swizzle (512 % 8 == 0)
  int brow = wg >> 3;                // 0..63
  int bcol = wg & 7;                 // 0..7
  int tid = threadIdx.x;
  int w = tid >> 6, lane = tid & 63;
  int g = lane >> 4, lr = lane & 15;
  int wr = w >> 1, wc = w & 1;
  const char* Abase = (const char*)(A + (size_t)brow * 128 * 1024);
  const char* Bbase = (const char*)(Bt + (size_t)bcol * 128 * 1024);
  f32x4 acc[4][4] = {};
  for (int kt = 0; kt < 16; ++kt) {
    int k0b = kt * 128;  // byte offset along K
#pragma unroll
    for (int i = 0; i < 4; ++i) {
      int j = w * 4 + i;             // 16 slots of 1 KiB
      int fo = j * 1024 + lane * 16; // linear LDS dest byte
      int row = fo >> 7;
      int cis = ((fo >> 4) & 7) ^ (row & 7);  // inverse-swizzled source chunk
      long srcoff = (long)row * 2048 + k0b + cis * 16;
      gload_lds16(Abase + srcoff, (char*)Asm + j * 1024);
      gload_lds16(Bbase + srcoff, (char*)Bsm + j * 1024);
    }
    __syncthreads();
#pragma unroll
    for (int ks = 0; ks < 2; ++ks) {
      bf16x8 af[4], bfr[4];
#pragma unroll
      for (int m = 0; m < 4; ++m) {
        int row = wr * 64 + m * 16 + lr;
        int ci = (ks * 4 + g) ^ (row & 7);
        af[m] = *(const bf16x8*)((const char*)Asm + row * 128 + ci * 16);
      }
#pragma unroll
      for (int n = 0; n < 4; ++n) {
        int row = wc * 64 + n * 16 + lr;
        int ci = (ks * 4 + g) ^ (row & 7);
        bfr[n] = *(const bf16x8*)((const char*)Bsm + row * 128 + ci * 16);
      }
#pragma unroll
      for (int m = 0; m < 4; ++m)
#pragma unroll
        for (int n = 0; n < 4; ++n)
          acc[m][n] = __builtin_amdgcn_mfma_f32_16x16x32_bf16(af[m], bfr[n], acc[m][n], 0, 0, 0);
    }
    __syncthreads();
  }
#pragma unroll
  for (int m = 0; m < 4; ++m) {
#pragma unroll
    for (int n = 0; n < 4; ++n) {
      int Cc = bcol * 128 + wc * 64 + n * 16 + lr;
      float bv = bias[Cc];
#pragma unroll
      for (int r = 0; r < 4; ++r) {
        int R = brow * 128 + wr * 64 + m * 16 + g * 4 + r;
        float v = acc[m][n][r] + bv;
        if (MODE == 0) {
          ((float*)out)[(size_t)R * 1024 + Cc] = v;
        } else if (MODE == 1) {
          int b = R >> 11, s = R & 2047, h = Cc >> 6, d = Cc & 63;
          ((ushort*)out)[(((size_t)(b * 16 + h) * 2048 + s) << 6) + d] = f2bf(v);
        } else {
          int b = R >> 11, s = R & 2047, h = Cc >> 6, d = Cc & 63;
          ((ushort*)out)[(((size_t)(b * 16 + h) * 64 + d) << 11) + s] = f2bf(v);
        }
      }
    }
  }
}

// ---------------- flash attention v4: swapped-QK 32x32, in-register softmax --------
// Grid 1024 = one 128-row q-tile per block (4 warps x 32 q-rows), 4 blocks/CU.
// S^T[kv][q] = K·Q^T via mfma_32x32x16(A=K-frag, B=Q-frag): lane owns column
// q=lane&31; kv lives in regs -> softmax is in-lane tree + one cross-half
// exchange. P^T -> PV B-operand via cvt_pk + permlane32_swap (T12).
// out^T[d][q] = V^T·P^T. K/V tiles [64][64] bf16 in LDS, XOR-swizzled (G21),
// double-buffered, one barrier per tile.
DI void stage2(const char* Kp, const char* Vp, char* Kd, char* Vd, int t0,
               int w, int lane) {
#pragma unroll
  for (int i = 0; i < 2; ++i) {
    int j = w * 2 + i;               // 8 slots of 1 KiB
    int fo = j * 1024 + lane * 16;   // linear LDS dest byte
    int row = fo >> 7;               // 0..63
    int ch = ((fo >> 4) & 7) ^ (row & 7);
    gload_lds16(Kp + (size_t)(t0 + row) * 128 + ch * 16, Kd + j * 1024);
    gload_lds16(Vp + (size_t)row * 4096 + (size_t)t0 * 2 + ch * 16, Vd + j * 1024);
  }
}

#define PACKP(pp, base, dst)                                \
  {                                                         \
    u32 a0 = cvtpk(pp[(base) + 0], pp[(base) + 1]);         \
    u32 b0 = cvtpk(pp[(base) + 4], pp[(base) + 5]);         \
    u32 a1 = cvtpk(pp[(base) + 2], pp[(base) + 3]);         \
    u32 b1 = cvtpk(pp[(base) + 6], pp[(base) + 7]);         \
    u32x2v r0 = permswap(a0, b0);                           \
    u32x2v r1 = permswap(a1, b1);                           \
    u32x4v f;                                               \
    f.x = r0.x; f.y = r1.x; f.z = r0.y; f.w = r1.y;         \
    dst = __builtin_bit_cast(bf16x8, f);                    \
  }

__global__ __launch_bounds__(256, 4) void k_attn(const ushort* __restrict__ Qb,
                                                 const ushort* __restrict__ Kb,
                                                 const ushort* __restrict__ Vt,
                                                 ushort* __restrict__ aout) {
  __shared__ ushort Ksm[2][4096];  // [buf][64 kv][64 d] bf16, swizzled
  __shared__ ushort Vsm[2][4096];  // [buf][64 d][64 kv] bf16, swizzled
  int L = blockIdx.x;              // 1024 blocks: 8 xcd x 8 bh x 16 qtile
  int xcd = L & 7, idx = L >> 3;
  int bh = xcd * 8 + (idx >> 4);
  int qt = idx & 15;
  int b = bh >> 4, h = bh & 15;
  int tid = threadIdx.x;
  int w = tid >> 6, lane = tid & 63, l31 = lane & 31, hi = lane >> 5;
  const ushort* Qp = Qb + (size_t)bh * 2048 * 64;
  const char* Kp = (const char*)(Kb + (size_t)bh * 2048 * 64);
  const char* Vp = (const char*)(Vt + (size_t)bh * 64 * 2048);
  const float sc = 0.18033688f;  // (1/8) * log2(e)

  int q0 = qt * 128 + w * 32;
  bf16x8 qf[4];
#pragma unroll
  for (int ks = 0; ks < 4; ++ks)
    qf[ks] = load_frag(Qp + (q0 + l31) * 64 + ks * 16 + hi * 8);
  f32x16 o0 = {}, o1 = {};
  float m_s = -1e30f, lsum = 0.f;

  stage2(Kp, Vp, (char*)Ksm[0], (char*)Vsm[0], 0, w, lane);
  __syncthreads();
  int cur = 0;
#pragma unroll 2
  for (int t = 0; t < 32; ++t) {
    if (t < 31)
      stage2(Kp, Vp, (char*)Ksm[cur ^ 1], (char*)Vsm[cur ^ 1], (t + 1) * 64, w, lane);
    const char* Kc = (const char*)Ksm[cur];
    const char* Vc = (const char*)Vsm[cur];
    // ---- QK^T (swapped): S^T[kv][q] ----
    f32x16 s0 = {}, s1 = {};
#pragma unroll
    for (int ks = 0; ks < 4; ++ks) {
      int ci = ((ks * 2 + hi) ^ (l31 & 7)) << 4;
      bf16x8 ka0 = *(const bf16x8*)(Kc + l31 * 128 + ci);
      bf16x8 ka1 = *(const bf16x8*)(Kc + (32 + l31) * 128 + ci);
      s0 = mfma32(ka0, qf[ks], s0);
      s1 = mfma32(ka1, qf[ks], s1);
    }
    // ---- in-register online softmax (log2 domain, scale folded) ----
    float mx[16];
#pragma unroll
    for (int i = 0; i < 16; ++i) mx[i] = fmaxf(s0[i], s1[i]);
#pragma unroll
    for (int st = 8; st >= 1; st >>= 1)
#pragma unroll
      for (int i = 0; i < st; ++i) mx[i] = fmaxf(mx[i], mx[i + st]);
    float pm = fmaxf(mx[0], __shfl_xor(mx[0], 32, 64)) * sc;
    if (__ballot(pm > m_s + 8.f)) {  // T13 defer-max
      float mnew = fmaxf(m_s, pm);
      float corr = __builtin_amdgcn_exp2f(m_s - mnew);
      m_s = mnew;
#pragma unroll
      for (int i = 0; i < 16; ++i) { o0[i] *= corr; o1[i] *= corr; }
      lsum *= corr;
    }
    float p0[16], p1[16];
#pragma unroll
    for (int i = 0; i < 16; ++i) {
      p0[i] = __builtin_amdgcn_exp2f(__builtin_fmaf(s0[i], sc, -m_s));
      p1[i] = __builtin_amdgcn_exp2f(__builtin_fmaf(s1[i], sc, -m_s));
    }
    float sm[16];
#pragma unroll
    for (int i = 0; i < 16; ++i) sm[i] = p0[i] + p1[i];
#pragma unroll
    for (int st = 8; st >= 1; st >>= 1)
#pragma unroll
      for (int i = 0; i < st; ++i) sm[i] += sm[i + st];
    lsum += sm[0] + __shfl_xor(sm[0], 32, 64);
    // ---- P^T -> B-fragments (in-register, T12) ----
    bf16x8 pb0, pb1, pb2, pb3;
    PACKP(p0, 0, pb0);
    PACKP(p0, 8, pb1);
    PACKP(p1, 0, pb2);
    PACKP(p1, 8, pb3);
    // ---- PV: out^T[d][q] += V^T · P^T ----
#pragma unroll
    for (int ks = 0; ks < 4; ++ks) {
      int ci = ((ks * 2 + hi) ^ (l31 & 7)) << 4;
      bf16x8 va0 = *(const bf16x8*)(Vc + l31 * 128 + ci);
      bf16x8 va1 = *(const bf16x8*)(Vc + (32 + l31) * 128 + ci);
      bf16x8 pb = (ks == 0) ? pb0 : (ks == 1) ? pb1 : (ks == 2) ? pb2 : pb3;
      o0 = mfma32(va0, pb, o0);
      o1 = mfma32(va1, pb, o1);
    }
    __syncthreads();
    cur ^= 1;
  }
  // ---- epilogue: lane owns row s = q0 + l31; d = (reg&3)+8*(reg>>2)+4*hi ----
  float rl = 1.f / lsum;
  ushort* orow = aout + ((size_t)b * 2048 + q0 + l31) * 1024 + h * 64;
#pragma unroll
  for (int r = 0; r < 8; ++r) {
    int d0 = ((2 * r) & 3) + 8 * ((2 * r) >> 2) + 4 * hi;
    *(u32*)(orow + d0) = cvtpk(o0[2 * r] * rl, o0[2 * r + 1] * rl);
    *(u32*)(orow + 32 + d0) = cvtpk(o1[2 * r] * rl, o1[2 * r + 1] * rl);
  }
}

// ---------------- launch ----------------
// ws layout (needs 72 MiB):
//   [0,16M)   xb  : x as bf16 [8192][1024]    (reused as attn-out after QKV)
//   [16,18M)  WqT  [18,20M) WkT  [20,22M) WvT  [22,24M) WoT   (bf16 [N][K])
//   [24,40M)  Qb [B,H,S,D] bf16
//   [40,56M)  Kb [B,H,S,D] bf16
//   [56,72M)  Vt [B,H,D,S] bf16
extern "C" void kernel_launch(void* const* d_in, const int* in_sizes, int n_in,
                              void* d_out, int out_size, void* d_ws, size_t ws_size,
                              hipStream_t stream) {
  const float* x  = (const float*)d_in[0];
  const float* Wq = (const float*)d_in[1];
  const float* bq = (const float*)d_in[2];
  const float* Wk = (const float*)d_in[3];
  const float* bk = (const float*)d_in[4];
  const float* Wv = (const float*)d_in[5];
  const float* bv = (const float*)d_in[6];
  const float* Wo = (const float*)d_in[7];
  const float* bo = (const float*)d_in[8];
  char* wsb = (char*)d_ws;
  ushort* xb   = (ushort*)(wsb);
  ushort* WqT  = (ushort*)(wsb + (16u << 20));
  ushort* WkT  = (ushort*)(wsb + (18u << 20));
  ushort* WvT  = (ushort*)(wsb + (20u << 20));
  ushort* WoT  = (ushort*)(wsb + (22u << 20));
  ushort* Qb   = (ushort*)(wsb + (24u << 20));
  ushort* Kb   = (ushort*)(wsb + (40u << 20));
  ushort* Vtb  = (ushort*)(wsb + (56u << 20));
  ushort* aout = xb;  // xb dead after the V projection

  k_convert_x<<<8192, 256, 0, stream>>>(x, xb);
  k_transpose_w4<<<1024, 256, 0, stream>>>(Wq, Wk, Wv, Wo, WqT, WkT, WvT, WoT);
  k_gemm<1><<<512, 256, 0, stream>>>(xb, WqT, bq, (void*)Qb);
  k_gemm<1><<<512, 256, 0, stream>>>(xb, WkT, bk, (void*)Kb);
  k_gemm<2><<<512, 256, 0, stream>>>(xb, WvT, bv, (void*)Vtb);
  k_attn<<<1024, 256, 0, stream>>>(Qb, Kb, Vtb, aout);
  k_gemm<0><<<512, 256, 0, stream>>>(aout, WoT, bo, d_out);
}